// Round 8
// baseline (196.800 us; speedup 1.0000x reference)
//
#include <hip/hip_runtime.h>
#include <hip/hip_bf16.h>

// B=2, S=2048, D=1024, H=16, DH=64
#define S_LEN   2048
#define D_MODEL 1024
#define NHEAD   16
#define DHEAD   64
#define M_ROWS  4096   // B*S
#define BHEADS  32     // B*H
#define MEG     1048576

typedef __attribute__((ext_vector_type(8)))  short short8;   // 8 bf16 (4 VGPRs)
typedef __attribute__((ext_vector_type(4)))  float f32x4;
typedef __attribute__((ext_vector_type(16))) float f32x16;
typedef __attribute__((ext_vector_type(4)))  unsigned short us4;
typedef __attribute__((ext_vector_type(2)))  unsigned int uint2v;
typedef __attribute__((ext_vector_type(4)))  unsigned int uint4v;

// fast native exp2 (single v_exp_f32) from ROCm device libs
extern "C" __device__ float __ocml_native_exp2_f32(float);

// fp32 -> bf16 round-to-nearest-even
__device__ __forceinline__ unsigned short f2b(float f) {
    unsigned int u = __builtin_bit_cast(unsigned int, f);
    return (unsigned short)((u + 0x7FFFu + ((u >> 16) & 1u)) >> 16);
}

// pack two fp32 -> two bf16 in one dword, RTNE (gfx950 v_cvt_pk_bf16_f32).
__device__ __forceinline__ unsigned int cvtpk(float lo, float hi) {
    unsigned int r;
    asm("v_cvt_pk_bf16_f32 %0, %1, %2" : "=v"(r) : "v"(lo), "v"(hi));
    return r;
}

__device__ __forceinline__ float b2f(unsigned short b) {
    return __builtin_bit_cast(float, (unsigned int)b << 16);
}

// async global->LDS, 16B per lane; LDS dest = wave-uniform base + lane*16
#define GLOAD16(gp, lp) __builtin_amdgcn_global_load_lds(                     \
        (const __attribute__((address_space(1))) void*)(gp),                  \
        (__attribute__((address_space(3))) void*)(lp), 16, 0, 0)

// Bank swizzle: logical 16B sub-block sb of row r lives at phys sb ^ ((r>>1)&3).
#define STAGE_OFS(lane) ((((lane) & 3) ^ (((lane) >> 3) & 3)) * 8)

#define ZERO16(v) do { _Pragma("unroll")                                      \
    for (int z_ = 0; z_ < 16; ++z_) (v)[z_] = 0.f; } while (0)

// ---------------------------------------------------------------------------
// Fused prep: z<4 -> transpose W z to bf16 Wt[n][k]; z==4 -> convert x to bf16
// ---------------------------------------------------------------------------
__global__ __launch_bounds__(256) void prep(
    const float* __restrict__ x, unsigned short* __restrict__ xb,
    const float* __restrict__ Wq, const float* __restrict__ Wk,
    const float* __restrict__ Wv, const float* __restrict__ Wo,
    unsigned short* __restrict__ Wqt, unsigned short* __restrict__ Wkt,
    unsigned short* __restrict__ Wvt, unsigned short* __restrict__ Wot)
{
    const int z = blockIdx.z;
    const int tx = threadIdx.x, ty = threadIdx.y;     // 32 x 8
    if (z == 4) {
        const int blk = blockIdx.y * 32 + blockIdx.x;     // 0..1023
        const int base = (blk * 256 + ty * 32 + tx) * 4;
        #pragma unroll
        for (int r = 0; r < 4; ++r) {
            const int i = base + r * (M_ROWS * D_MODEL / 4);
            const float4 v = *(const float4*)&x[i];
            us4 o;
            o.x = f2b(v.x); o.y = f2b(v.y); o.z = f2b(v.z); o.w = f2b(v.w);
            *(us4*)&xb[i] = o;
        }
        return;
    }
    __shared__ float tile[32][33];
    const float* W = z == 0 ? Wq : (z == 1 ? Wk : (z == 2 ? Wv : Wo));
    unsigned short* Wt = z == 0 ? Wqt : (z == 1 ? Wkt : (z == 2 ? Wvt : Wot));
    const int n0 = blockIdx.x * 32, k0 = blockIdx.y * 32;
    #pragma unroll
    for (int i = 0; i < 4; ++i)
        tile[ty + i * 8][tx] = W[(size_t)(k0 + ty + i * 8) * D_MODEL + n0 + tx];
    __syncthreads();
    #pragma unroll
    for (int i = 0; i < 4; ++i)
        Wt[(size_t)(n0 + ty + i * 8) * D_MODEL + k0 + tx] = f2b(tile[tx][ty + i * 8]);
}

// ---------------------------------------------------------------------------
// Fused Q/K/V projection GEMM (z = 0/1/2), double-buffered single-barrier.
// R8: 32x32x16 MFMA (4060 vs 3380 FLOP/cyc pipe rate, half the MFMA instrs).
// Wave sub-tile 64x64 = 2x2 MFMA tiles. C-layout: col = bn+wn*64+ni*32+q5,
// row = bm+wm*64+mi*32+(reg&3)+8*(reg>>2)+4*hi (verified layout from attn).
// ---------------------------------------------------------------------------
__global__ __launch_bounds__(256) void gemm_qkv(
    const unsigned short* __restrict__ xb,
    const unsigned short* __restrict__ Wqt, const unsigned short* __restrict__ Wkt,
    const unsigned short* __restrict__ Wvt,
    const float* __restrict__ bq, const float* __restrict__ bk,
    const float* __restrict__ bv,
    unsigned short* __restrict__ Qb, unsigned short* __restrict__ Kb,
    unsigned short* __restrict__ Vt)
{
    __shared__ unsigned short As[2][128][32];
    __shared__ unsigned short Bs[2][128][32];

    const int z = blockIdx.z;
    const unsigned short* Wt = z == 0 ? Wqt : (z == 1 ? Wkt : Wvt);
    const float* bias = z == 0 ? bq : (z == 1 ? bk : bv);

    const int t = threadIdx.x, lane = t & 63, w = t >> 6;
    const int q5 = lane & 31, hi = lane >> 5;
    const int wm = w >> 1, wn = w & 1;
    const int bm = blockIdx.y * 128, bn = blockIdx.x * 128;
    const int lr = lane >> 2, lc = STAGE_OFS(lane);
    const int sw = (q5 >> 1) & 3;
    int sbo[4];
    #pragma unroll
    for (int sb = 0; sb < 4; ++sb) sbo[sb] = (sb ^ sw) * 8;

    f32x16 acc[2][2];
    ZERO16(acc[0][0]); ZERO16(acc[0][1]); ZERO16(acc[1][0]); ZERO16(acc[1][1]);

    #pragma unroll
    for (int i = 0; i < 2; ++i) {
        const int c = 2 * w + i;
        GLOAD16(xb + (size_t)(bm + c * 16 + lr) * D_MODEL + lc, &As[0][c * 16][0]);
        GLOAD16(Wt + (size_t)(bn + c * 16 + lr) * D_MODEL + lc, &Bs[0][c * 16][0]);
    }
    __syncthreads();

    for (int it = 0; it < 32; ++it) {
        const int cur = it & 1;
        if (it + 1 < 32) {
            const int kt = (it + 1) * 32;
            #pragma unroll
            for (int i = 0; i < 2; ++i) {
                const int c = 2 * w + i;
                GLOAD16(xb + (size_t)(bm + c * 16 + lr) * D_MODEL + kt + lc,
                        &As[cur ^ 1][c * 16][0]);
                GLOAD16(Wt + (size_t)(bn + c * 16 + lr) * D_MODEL + kt + lc,
                        &Bs[cur ^ 1][c * 16][0]);
            }
        }

        short8 af[2][2], bfr[2][2];
        #pragma unroll
        for (int mi = 0; mi < 2; ++mi)
            #pragma unroll
            for (int kk = 0; kk < 2; ++kk)
                af[mi][kk] = *(const short8*)
                    &As[cur][wm * 64 + mi * 32 + q5][sbo[kk * 2 + hi]];
        #pragma unroll
        for (int ni = 0; ni < 2; ++ni)
            #pragma unroll
            for (int kk = 0; kk < 2; ++kk)
                bfr[ni][kk] = *(const short8*)
                    &Bs[cur][wn * 64 + ni * 32 + q5][sbo[kk * 2 + hi]];
        #pragma unroll
        for (int kk = 0; kk < 2; ++kk)
            #pragma unroll
            for (int mi = 0; mi < 2; ++mi)
                #pragma unroll
                for (int ni = 0; ni < 2; ++ni)
                    acc[mi][ni] = __builtin_amdgcn_mfma_f32_32x32x16_bf16(
                        af[mi][kk], bfr[ni][kk], acc[mi][ni], 0, 0, 0);

        __syncthreads();
    }

    float bb[2];
    #pragma unroll
    for (int ni = 0; ni < 2; ++ni)
        bb[ni] = bias[bn + wn * 64 + ni * 32 + q5];
    const float scale = (z == 0) ? 0.18033688011112042f : 1.0f;  // (1/8)*log2e

    if (z < 2) {
        unsigned short* Out = (z == 0) ? Qb : Kb;
        #pragma unroll
        for (int mi = 0; mi < 2; ++mi)
            #pragma unroll
            for (int ni = 0; ni < 2; ++ni) {
                const int col = bn + wn * 64 + ni * 32 + q5;
                const int h = col >> 6, d = col & 63;
                #pragma unroll
                for (int reg = 0; reg < 16; ++reg) {
                    const int row = bm + wm * 64 + mi * 32
                                  + (reg & 3) + 8 * (reg >> 2) + 4 * hi;
                    const int b = row >> 11, s = row & 2047;
                    Out[(((size_t)(b * NHEAD + h)) * S_LEN + s) * DHEAD + d] =
                        f2b((acc[mi][ni][reg] + bb[ni]) * scale);
                }
            }
    } else {
        #pragma unroll
        for (int mi = 0; mi < 2; ++mi)
            #pragma unroll
            for (int ni = 0; ni < 2; ++ni) {
                const int col = bn + wn * 64 + ni * 32 + q5;
                const int h = col >> 6, d = col & 63;
                #pragma unroll
                for (int g = 0; g < 4; ++g) {
                    const int row0 = bm + wm * 64 + mi * 32 + 8 * g + 4 * hi;
                    const int b = row0 >> 11, s0 = row0 & 2047;
                    us4 pk;
                    pk.x = f2b(acc[mi][ni][4 * g + 0] + bb[ni]);
                    pk.y = f2b(acc[mi][ni][4 * g + 1] + bb[ni]);
                    pk.z = f2b(acc[mi][ni][4 * g + 2] + bb[ni]);
                    pk.w = f2b(acc[mi][ni][4 * g + 3] + bb[ni]);
                    *(us4*)&Vt[(((size_t)(b * NHEAD + h)) * DHEAD + d) * S_LEN + s0] = pk;
                }
            }
    }
}

// ---------------------------------------------------------------------------
// Output projection: 64x128 tile, 32x32x16 MFMA (R8), double-buffered.
// Wave sub-tile 32m x 64n.
// ---------------------------------------------------------------------------
__global__ __launch_bounds__(256) void gemm_out(
    const unsigned short* __restrict__ Ab, const unsigned short* __restrict__ Wot,
    const float* __restrict__ bo, float* __restrict__ out)
{
    __shared__ unsigned short As[2][64][32];
    __shared__ unsigned short Bs[2][128][32];

    const int t = threadIdx.x, lane = t & 63, w = t >> 6;
    const int q5 = lane & 31, hi = lane >> 5;
    const int wm = w & 1, wn = w >> 1;
    const int bm = blockIdx.y * 64, bn = blockIdx.x * 128;
    const int lr = lane >> 2, lc = STAGE_OFS(lane);
    const int sw = (q5 >> 1) & 3;
    int sbo[4];
    #pragma unroll
    for (int sb = 0; sb < 4; ++sb) sbo[sb] = (sb ^ sw) * 8;

    f32x16 acc[2];
    ZERO16(acc[0]); ZERO16(acc[1]);

    GLOAD16(Ab + (size_t)(bm + w * 16 + lr) * D_MODEL + lc, &As[0][w * 16][0]);
    #pragma unroll
    for (int i = 0; i < 2; ++i)
        GLOAD16(Wot + (size_t)(bn + w * 32 + i * 16 + lr) * D_MODEL + lc,
                &Bs[0][w * 32 + i * 16][0]);
    __syncthreads();

    for (int it = 0; it < 32; ++it) {
        const int cur = it & 1;
        if (it + 1 < 32) {
            const int kt = (it + 1) * 32;
            GLOAD16(Ab + (size_t)(bm + w * 16 + lr) * D_MODEL + kt + lc,
                    &As[cur ^ 1][w * 16][0]);
            #pragma unroll
            for (int i = 0; i < 2; ++i)
                GLOAD16(Wot + (size_t)(bn + w * 32 + i * 16 + lr) * D_MODEL + kt + lc,
                        &Bs[cur ^ 1][w * 32 + i * 16][0]);
        }

        short8 af[2], bfr[2][2];
        #pragma unroll
        for (int kk = 0; kk < 2; ++kk)
            af[kk] = *(const short8*)&As[cur][wm * 32 + q5][sbo[kk * 2 + hi]];
        #pragma unroll
        for (int ni = 0; ni < 2; ++ni)
            #pragma unroll
            for (int kk = 0; kk < 2; ++kk)
                bfr[ni][kk] = *(const short8*)
                    &Bs[cur][wn * 64 + ni * 32 + q5][sbo[kk * 2 + hi]];
        #pragma unroll
        for (int kk = 0; kk < 2; ++kk)
            #pragma unroll
            for (int ni = 0; ni < 2; ++ni)
                acc[ni] = __builtin_amdgcn_mfma_f32_32x32x16_bf16(
                    af[kk], bfr[ni][kk], acc[ni], 0, 0, 0);

        __syncthreads();
    }

    float bb[2];
    #pragma unroll
    for (int ni = 0; ni < 2; ++ni)
        bb[ni] = bo[bn + wn * 64 + ni * 32 + q5];

    #pragma unroll
    for (int ni = 0; ni < 2; ++ni) {
        const int col = bn + wn * 64 + ni * 32 + q5;
        #pragma unroll
        for (int reg = 0; reg < 16; ++reg) {
            const int row = bm + wm * 32 + (reg & 3) + 8 * (reg >> 2) + 4 * hi;
            out[(size_t)row * D_MODEL + col] = acc[ni][reg] + bb[ni];
        }
    }
}

// ---------------------------------------------------------------------------
// MFMA flash attention (R6 version -- best measured, 46.2us):
// S^T form, 32x32x16, in-register P transpose (permlane32_swap), no split-S,
// fused normalization, QK one-tile-ahead pipeline, triple-buffered KV,
// l-sum via MFMA with all-ones B.
// ---------------------------------------------------------------------------
__global__ __launch_bounds__(256, 2) void attn_mfma(
    const unsigned short* __restrict__ Q, const unsigned short* __restrict__ K,
    const unsigned short* __restrict__ V, unsigned short* __restrict__ Cx)
{
    __shared__ __align__(16) unsigned char raw[49152];
    // buf b (b=0..2): Ks at raw + b*16384 ([2][64][32] ushorts), Vs at +8192
    unsigned short (*Qs)[128][32] = (unsigned short (*)[128][32])raw; // = buf0

    const int t = threadIdx.x, lane = t & 63, w = t >> 6;
    const int q5 = lane & 31, hi = lane >> 5;
    const int lr = lane >> 2, lcs = STAGE_OFS(lane);
    // T1: XCD-chunked swizzle of the 512-block grid
    const int id  = blockIdx.y * 16 + blockIdx.x;   // dispatch-linear id
    const int swz = (id & 7) * 64 + (id >> 3);      // bijective remap
    const int q0 = (swz & 15) * 128, bh = swz >> 4;
    const int sw = (q5 >> 1) & 3;              // row-swizzle for frag reads
    int sbo[4];
    #pragma unroll
    for (int sb = 0; sb < 4; ++sb) sbo[sb] = (sb ^ sw) * 8;

    const unsigned short* Qh = Q + (size_t)bh * (S_LEN * DHEAD);
    const unsigned short* Kh = K + (size_t)bh * (S_LEN * DHEAD);
    const unsigned short* Vh = V + (size_t)bh * (DHEAD * S_LEN);

    // stage Q tile once into buf0 alias: wave w stages rows w*32..w*32+31
    #pragma unroll
    for (int i = 0; i < 2; ++i)
        #pragma unroll
        for (int c = 0; c < 2; ++c)
            GLOAD16(Qh + (size_t)(q0 + w * 32 + c * 16 + lr) * DHEAD + i * 32 + lcs,
                    &Qs[i][w * 32 + c * 16][0]);
    __syncthreads();

    // hoist Q B-frags into registers
    short8 qf[4];
    #pragma unroll
    for (int c = 0; c < 4; ++c)
        qf[c] = *(const short8*)&Qs[c >> 1][w * 32 + q5][sbo[(c & 1) * 2 + hi]];
    __syncthreads();                           // Qs dead; buf0 reusable

    // all-ones B-frag (bf16 1.0 = 0x3F80) for the l-sum MFMA
    short8 onesf;
    #pragma unroll
    for (int j = 0; j < 8; ++j) onesf[j] = (short)0x3F80;

    // stage K/V tile `IT` into buffer BUF (8KB Ks + 8KB Vs)
    #define STAGE_KV(IT, BUF) do {                                            \
        const int kt_ = (IT) * 64;                                            \
        unsigned short* ksb_ = (unsigned short*)(raw + (BUF) * 16384);        \
        unsigned short* vsb_ = ksb_ + 4096;                                   \
        _Pragma("unroll")                                                     \
        for (int i_ = 0; i_ < 2; ++i_) {                                      \
            GLOAD16(Kh + (size_t)(kt_ + w * 16 + lr) * DHEAD + i_ * 32 + lcs, \
                    ksb_ + (i_ * 64 + w * 16) * 32);                          \
            GLOAD16(Vh + (size_t)(w * 16 + lr) * S_LEN + kt_ + i_ * 32 + lcs, \
                    vsb_ + (i_ * 64 + w * 16) * 32);                          \
        }                                                                     \
    } while (0)

    // QK chain for tile IT from its buffer into SF (must be pre-zeroed)
    #define QK_CHAIN(IT, SF) do {                                             \
        const unsigned short* kn_ = (const unsigned short*)                   \
            (raw + ((IT) % 3) * 16384);                                       \
        _Pragma("unroll")                                                     \
        for (int c_ = 0; c_ < 4; ++c_) {                                      \
            _Pragma("unroll")                                                 \
            for (int mt_ = 0; mt_ < 2; ++mt_) {                               \
                const short8 kf_ = *(const short8*)                           \
                    &kn_[((c_ >> 1) * 64 + mt_ * 32 + q5) * 32                \
                         + sbo[(c_ & 1) * 2 + hi]];                           \
                SF[mt_] = __builtin_amdgcn_mfma_f32_32x32x16_bf16(            \
                    kf_, qf[c_], SF[mt_], 0, 0, 0);                           \
            }                                                                 \
        }                                                                     \
    } while (0)

    f32x16 acc[2];     // O strip: [d-tile][16 regs], row=q, col=d
    f32x16 acc_l;      // l (row-sum) via P x ones; same row layout as acc
    ZERO16(acc[0]); ZERO16(acc[1]); ZERO16(acc_l);
    f32x16 sfA[2], sfB[2];

    // prologue: KV(0) resident; sfA = S(0); KV(1) in flight
    STAGE_KV(0, 0);
    __syncthreads();
    ZERO16(sfA[0]); ZERO16(sfA[1]);
    QK_CHAIN(0, sfA);
    STAGE_KV(1, 1);

    // Region R(it): barrier (drains stage(it+1)); issue stage(it+2);
    // QK(it+1) -> SFN; exp/pack/PV/l(it) from SFC.
    #define REGION(IT, SFC, SFN, DOQK) do {                                   \
        __syncthreads();                                                      \
        if ((IT) + 2 < 32) STAGE_KV((IT) + 2, ((IT) + 2) % 3);                \
        if (DOQK) {                                                           \
            ZERO16(SFN[0]); ZERO16(SFN[1]);                                   \
            QK_CHAIN((IT) + 1, SFN);                                          \
        }                                                                     \
        const unsigned short* vs_ = (const unsigned short*)                   \
            (raw + ((IT) % 3) * 16384) + 4096;                                \
        _Pragma("unroll")                                                     \
        for (int c = 0; c < 4; ++c) {                                         \
            const int mt = c >> 1, pp = c & 1;                                \
            float p[8];                                                       \
            _Pragma("unroll")                                                 \
            for (int e = 0; e < 8; ++e)                                       \
                p[e] = __ocml_native_exp2_f32(SFC[mt][pp * 8 + e]);           \
            const unsigned int dA = cvtpk(p[0], p[1]);                        \
            const unsigned int dB = cvtpk(p[2], p[3]);                        \
            const unsigned int sA = cvtpk(p[4], p[5]);                        \
            const unsigned int sB = cvtpk(p[6], p[7]);                        \
            const uint2v wA = __builtin_amdgcn_permlane32_swap(dA, sA, false, false); \
            const uint2v wB = __builtin_amdgcn_permlane32_swap(dB, sB, false, false); \
            uint4v wrds;                                                      \
            wrds.x = wA.x; wrds.y = wB.x; wrds.z = wA.y; wrds.w = wB.y;       \
            const short8 pf = __builtin_bit_cast(short8, wrds);               \
            acc_l = __builtin_amdgcn_mfma_f32_32x32x16_bf16(                  \
                pf, onesf, acc_l, 0, 0, 0);                                   \
            _Pragma("unroll")                                                 \
            for (int nt = 0; nt < 2; ++nt) {                                  \
                const short8 vf = *(const short8*)                            \
                    &vs_[((c >> 1) * 64 + nt * 32 + q5) * 32                  \
                         + sbo[(c & 1) * 2 + hi]];                            \
                acc[nt] = __builtin_amdgcn_mfma_f32_32x32x16_bf16(            \
                    pf, vf, acc[nt], 0, 0, 0);                                \
            }                                                                 \
        }                                                                     \
    } while (0)

    for (int itp = 0; itp < 16; ++itp) {
        const int it0 = itp * 2;
        REGION(it0, sfA, sfB, true);
        REGION(it0 + 1, sfB, sfA, (it0 + 2) < 32);
    }
    #undef REGION
    #undef QK_CHAIN
    #undef STAGE_KV

    // ---- epilogue: l is complete per-lane in acc_l; normalize + write ----
    const int b = bh >> 4, h = bh & 15;
    #pragma unroll
    for (int reg = 0; reg < 16; ++reg) {
        const int row = (reg & 3) + 8 * (reg >> 2) + 4 * hi;
        const float inv = 1.f / acc_l[reg];
        const int q = q0 + w * 32 + row;       // s index within this head
        unsigned short* dst = &Cx[((size_t)(b * S_LEN + q)) * D_MODEL + h * 64];
        dst[q5]      = f2b(acc[0][reg] * inv);
        dst[32 + q5] = f2b(acc[1][reg] * inv);
    }
}

// ---------------------------------------------------------------------------
extern "C" void kernel_launch(void* const* d_in, const int* in_sizes, int n_in,
                              void* d_out, int out_size, void* d_ws, size_t ws_size,
                              hipStream_t stream)
{
    const float* x  = (const float*)d_in[0];
    const float* Wq = (const float*)d_in[1];
    const float* bq = (const float*)d_in[2];
    const float* Wk = (const float*)d_in[3];
    const float* bk = (const float*)d_in[4];
    const float* Wv = (const float*)d_in[5];
    const float* bv = (const float*)d_in[6];
    const float* Wo = (const float*)d_in[7];
    const float* bo = (const float*)d_in[8];
    float* out = (float*)d_out;

    // ws layout (ushort units), 40MB total. Cxb ALIASES xb (xb dead after
    // gemm_qkv; attn writes Cxb, gemm_out reads it).
    unsigned short* base = (unsigned short*)d_ws;
    unsigned short* Wot   = base;                   //  0M .. 1M
    unsigned short* Qb    = base + 1 * MEG;         //  1M .. 5M
    unsigned short* Kb    = base + 5 * MEG;         //  5M .. 9M
    unsigned short* Vt    = base + 9 * MEG;         //  9M ..13M
    unsigned short* xb    = base + 13 * MEG;        // 13M ..17M
    unsigned short* Wqt   = base + 17 * MEG;        // 17M ..18M
    unsigned short* Wkt   = base + 18 * MEG;        // 18M ..19M
    unsigned short* Wvt   = base + 19 * MEG;        // 19M ..20M
    unsigned short* Cxb   = xb;                     // aliases xb

    prep<<<dim3(32, 32, 5), dim3(32, 8), 0, stream>>>(
        x, xb, Wq, Wk, Wv, Wo, Wqt, Wkt, Wvt, Wot);

    gemm_qkv<<<dim3(D_MODEL / 128, M_ROWS / 128, 3), dim3(256), 0, stream>>>(
        xb, Wqt, Wkt, Wvt, bq, bk, bv, Qb, Kb, Vt);

    attn_mfma<<<dim3(S_LEN / 128, BHEADS), dim3(256), 0, stream>>>(
        Qb, Kb, Vt, Cxb);

    gemm_out<<<dim3(D_MODEL / 128, M_ROWS / 64), dim3(256), 0, stream>>>(
        Cxb, Wot, bo, out);
}

// Round 9
// 190.956 us; speedup vs baseline: 1.0306x; 1.0306x over previous
//
#include <hip/hip_runtime.h>
#include <hip/hip_bf16.h>

// B=2, S=2048, D=1024, H=16, DH=64
#define S_LEN   2048
#define D_MODEL 1024
#define NHEAD   16
#define DHEAD   64
#define M_ROWS  4096   // B*S
#define BHEADS  32     // B*H
#define MEG     1048576

typedef __attribute__((ext_vector_type(8)))  short short8;   // 8 bf16 (4 VGPRs)
typedef __attribute__((ext_vector_type(4)))  float f32x4;
typedef __attribute__((ext_vector_type(16))) float f32x16;
typedef __attribute__((ext_vector_type(4)))  unsigned short us4;
typedef __attribute__((ext_vector_type(2)))  unsigned int uint2v;
typedef __attribute__((ext_vector_type(4)))  unsigned int uint4v;

// fast native exp2 (single v_exp_f32) from ROCm device libs
extern "C" __device__ float __ocml_native_exp2_f32(float);

// fp32 -> bf16 round-to-nearest-even
__device__ __forceinline__ unsigned short f2b(float f) {
    unsigned int u = __builtin_bit_cast(unsigned int, f);
    return (unsigned short)((u + 0x7FFFu + ((u >> 16) & 1u)) >> 16);
}

// pack two fp32 -> two bf16 in one dword, RTNE (gfx950 v_cvt_pk_bf16_f32).
__device__ __forceinline__ unsigned int cvtpk(float lo, float hi) {
    unsigned int r;
    asm("v_cvt_pk_bf16_f32 %0, %1, %2" : "=v"(r) : "v"(lo), "v"(hi));
    return r;
}

__device__ __forceinline__ float b2f(unsigned short b) {
    return __builtin_bit_cast(float, (unsigned int)b << 16);
}

// async global->LDS, 16B per lane; LDS dest = wave-uniform base + lane*16
#define GLOAD16(gp, lp) __builtin_amdgcn_global_load_lds(                     \
        (const __attribute__((address_space(1))) void*)(gp),                  \
        (__attribute__((address_space(3))) void*)(lp), 16, 0, 0)

// Bank swizzle: logical 16B sub-block sb of row r lives at phys sb ^ ((r>>1)&3).
#define STAGE_OFS(lane) ((((lane) & 3) ^ (((lane) >> 3) & 3)) * 8)

#define ZERO16(v) do { _Pragma("unroll")                                      \
    for (int z_ = 0; z_ < 16; ++z_) (v)[z_] = 0.f; } while (0)

// ---------------------------------------------------------------------------
// Fused prep: z<4 -> transpose W z to bf16 Wt[n][k]; z==4 -> convert x to bf16
// ---------------------------------------------------------------------------
__global__ __launch_bounds__(256) void prep(
    const float* __restrict__ x, unsigned short* __restrict__ xb,
    const float* __restrict__ Wq, const float* __restrict__ Wk,
    const float* __restrict__ Wv, const float* __restrict__ Wo,
    unsigned short* __restrict__ Wqt, unsigned short* __restrict__ Wkt,
    unsigned short* __restrict__ Wvt, unsigned short* __restrict__ Wot)
{
    const int z = blockIdx.z;
    const int tx = threadIdx.x, ty = threadIdx.y;     // 32 x 8
    if (z == 4) {
        const int blk = blockIdx.y * 32 + blockIdx.x;     // 0..1023
        const int base = (blk * 256 + ty * 32 + tx) * 4;
        #pragma unroll
        for (int r = 0; r < 4; ++r) {
            const int i = base + r * (M_ROWS * D_MODEL / 4);
            const float4 v = *(const float4*)&x[i];
            us4 o;
            o.x = f2b(v.x); o.y = f2b(v.y); o.z = f2b(v.z); o.w = f2b(v.w);
            *(us4*)&xb[i] = o;
        }
        return;
    }
    __shared__ float tile[32][33];
    const float* W = z == 0 ? Wq : (z == 1 ? Wk : (z == 2 ? Wv : Wo));
    unsigned short* Wt = z == 0 ? Wqt : (z == 1 ? Wkt : (z == 2 ? Wvt : Wot));
    const int n0 = blockIdx.x * 32, k0 = blockIdx.y * 32;
    #pragma unroll
    for (int i = 0; i < 4; ++i)
        tile[ty + i * 8][tx] = W[(size_t)(k0 + ty + i * 8) * D_MODEL + n0 + tx];
    __syncthreads();
    #pragma unroll
    for (int i = 0; i < 4; ++i)
        Wt[(size_t)(n0 + ty + i * 8) * D_MODEL + k0 + tx] = f2b(tile[tx][ty + i * 8]);
}

// ---------------------------------------------------------------------------
// Fused Q/K/V projection GEMM, double-buffered single-barrier, 16x16x32.
// R9: T1 XCD-chunked swizzle over the full 768-block grid (768 = 8 x 96):
// each XCD gets 96 consecutive logical tiles -> the 8 x-blocks sharing an
// A-panel run on ONE XCD (A fetched once) and each z's 2MB B stays resident
// in that XCD's L2 (was: spread over all 8 L2s).
// ---------------------------------------------------------------------------
__global__ __launch_bounds__(256) void gemm_qkv(
    const unsigned short* __restrict__ xb,
    const unsigned short* __restrict__ Wqt, const unsigned short* __restrict__ Wkt,
    const unsigned short* __restrict__ Wvt,
    const float* __restrict__ bq, const float* __restrict__ bk,
    const float* __restrict__ bv,
    unsigned short* __restrict__ Qb, unsigned short* __restrict__ Kb,
    unsigned short* __restrict__ Vt)
{
    __shared__ unsigned short As[2][128][32];
    __shared__ unsigned short Bs[2][128][32];

    // T1 swizzle: hw id -> contiguous logical chunk per XCD (bijective).
    const int id  = (blockIdx.z * 32 + blockIdx.y) * 8 + blockIdx.x;  // 0..767
    const int swz = (id & 7) * 96 + (id >> 3);
    const int z   = swz >> 8;                 // logical z = swz / 256
    const int rem = swz & 255;
    const int bm  = (rem >> 3) * 128;         // logical y
    const int bn  = (rem & 7) * 128;          // logical x

    const unsigned short* Wt = z == 0 ? Wqt : (z == 1 ? Wkt : Wvt);
    const float* bias = z == 0 ? bq : (z == 1 ? bk : bv);

    const int t = threadIdx.x, lane = t & 63, w = t >> 6;
    const int wm = w >> 1, wn = w & 1;
    const int lr = lane >> 2, lc = STAGE_OFS(lane);
    const int lm = lane & 15, quad = lane >> 4;
    const int qo = (quad ^ ((lm >> 1) & 3)) * 8;      // swizzled frag offset

    f32x4 acc[4][4] = {};

    #pragma unroll
    for (int i = 0; i < 2; ++i) {
        const int c = 2 * w + i;
        GLOAD16(xb + (size_t)(bm + c * 16 + lr) * D_MODEL + lc, &As[0][c * 16][0]);
        GLOAD16(Wt + (size_t)(bn + c * 16 + lr) * D_MODEL + lc, &Bs[0][c * 16][0]);
    }
    __syncthreads();

    for (int it = 0; it < 32; ++it) {
        const int cur = it & 1;
        if (it + 1 < 32) {
            const int kt = (it + 1) * 32;
            #pragma unroll
            for (int i = 0; i < 2; ++i) {
                const int c = 2 * w + i;
                GLOAD16(xb + (size_t)(bm + c * 16 + lr) * D_MODEL + kt + lc,
                        &As[cur ^ 1][c * 16][0]);
                GLOAD16(Wt + (size_t)(bn + c * 16 + lr) * D_MODEL + kt + lc,
                        &Bs[cur ^ 1][c * 16][0]);
            }
        }

        short8 af[4], bfr[4];
        #pragma unroll
        for (int mi = 0; mi < 4; ++mi)
            af[mi] = *(const short8*)&As[cur][wm * 64 + mi * 16 + lm][qo];
        #pragma unroll
        for (int ni = 0; ni < 4; ++ni)
            bfr[ni] = *(const short8*)&Bs[cur][wn * 64 + ni * 16 + lm][qo];
        #pragma unroll
        for (int mi = 0; mi < 4; ++mi)
            #pragma unroll
            for (int ni = 0; ni < 4; ++ni)
                acc[mi][ni] = __builtin_amdgcn_mfma_f32_16x16x32_bf16(
                    af[mi], bfr[ni], acc[mi][ni], 0, 0, 0);

        __syncthreads();
    }

    float bb[4];
    #pragma unroll
    for (int ni = 0; ni < 4; ++ni)
        bb[ni] = bias[bn + wn * 64 + ni * 16 + lm];
    const float scale = (z == 0) ? 0.18033688011112042f : 1.0f;  // (1/8)*log2e

    if (z < 2) {
        unsigned short* Out = (z == 0) ? Qb : Kb;
        #pragma unroll
        for (int mi = 0; mi < 4; ++mi)
            #pragma unroll
            for (int r = 0; r < 4; ++r) {
                const int row = bm + wm * 64 + mi * 16 + quad * 4 + r;
                const int b = row >> 11, s = row & 2047;
                #pragma unroll
                for (int ni = 0; ni < 4; ++ni) {
                    const int col = bn + wn * 64 + ni * 16 + lm;
                    const int h = col >> 6, d = col & 63;
                    Out[(((size_t)(b * NHEAD + h)) * S_LEN + s) * DHEAD + d] =
                        f2b((acc[mi][ni][r] + bb[ni]) * scale);
                }
            }
    } else {
        #pragma unroll
        for (int mi = 0; mi < 4; ++mi) {
            const int row0 = bm + wm * 64 + mi * 16 + quad * 4;
            const int b = row0 >> 11, s0 = row0 & 2047;
            #pragma unroll
            for (int ni = 0; ni < 4; ++ni) {
                const int col = bn + wn * 64 + ni * 16 + lm;
                const int h = col >> 6, d = col & 63;
                us4 pk;
                pk.x = f2b(acc[mi][ni][0] + bb[ni]);
                pk.y = f2b(acc[mi][ni][1] + bb[ni]);
                pk.z = f2b(acc[mi][ni][2] + bb[ni]);
                pk.w = f2b(acc[mi][ni][3] + bb[ni]);
                *(us4*)&Vt[(((size_t)(b * NHEAD + h)) * DHEAD + d) * S_LEN + s0] = pk;
            }
        }
    }
}

// ---------------------------------------------------------------------------
// Output projection: 64x128 tile, double-buffered single-barrier, 16x16x32.
// R9: T1 XCD-chunked swizzle (512 = 8 x 64).
// ---------------------------------------------------------------------------
__global__ __launch_bounds__(256) void gemm_out(
    const unsigned short* __restrict__ Ab, const unsigned short* __restrict__ Wot,
    const float* __restrict__ bo, float* __restrict__ out)
{
    __shared__ unsigned short As[2][64][32];
    __shared__ unsigned short Bs[2][128][32];

    // T1 swizzle
    const int id  = blockIdx.y * 8 + blockIdx.x;    // 0..511
    const int swz = (id & 7) * 64 + (id >> 3);
    const int bm  = (swz >> 3) * 64;
    const int bn  = (swz & 7) * 128;

    const int t = threadIdx.x, lane = t & 63, w = t >> 6;
    const int wm = w & 1, wn = w >> 1;
    const int lr = lane >> 2, lc = STAGE_OFS(lane);
    const int lm = lane & 15, quad = lane >> 4;
    const int qo = (quad ^ ((lm >> 1) & 3)) * 8;

    f32x4 acc[2][4] = {};

    GLOAD16(Ab + (size_t)(bm + w * 16 + lr) * D_MODEL + lc, &As[0][w * 16][0]);
    #pragma unroll
    for (int i = 0; i < 2; ++i)
        GLOAD16(Wot + (size_t)(bn + w * 32 + i * 16 + lr) * D_MODEL + lc,
                &Bs[0][w * 32 + i * 16][0]);
    __syncthreads();

    for (int it = 0; it < 32; ++it) {
        const int cur = it & 1;
        if (it + 1 < 32) {
            const int kt = (it + 1) * 32;
            GLOAD16(Ab + (size_t)(bm + w * 16 + lr) * D_MODEL + kt + lc,
                    &As[cur ^ 1][w * 16][0]);
            #pragma unroll
            for (int i = 0; i < 2; ++i)
                GLOAD16(Wot + (size_t)(bn + w * 32 + i * 16 + lr) * D_MODEL + kt + lc,
                        &Bs[cur ^ 1][w * 32 + i * 16][0]);
        }

        short8 af[2], bfr[4];
        #pragma unroll
        for (int mi = 0; mi < 2; ++mi)
            af[mi] = *(const short8*)&As[cur][wm * 32 + mi * 16 + lm][qo];
        #pragma unroll
        for (int ni = 0; ni < 4; ++ni)
            bfr[ni] = *(const short8*)&Bs[cur][wn * 64 + ni * 16 + lm][qo];
        #pragma unroll
        for (int mi = 0; mi < 2; ++mi)
            #pragma unroll
            for (int ni = 0; ni < 4; ++ni)
                acc[mi][ni] = __builtin_amdgcn_mfma_f32_16x16x32_bf16(
                    af[mi], bfr[ni], acc[mi][ni], 0, 0, 0);

        __syncthreads();
    }

    float bb[4];
    #pragma unroll
    for (int ni = 0; ni < 4; ++ni)
        bb[ni] = bo[bn + wn * 64 + ni * 16 + lm];

    #pragma unroll
    for (int mi = 0; mi < 2; ++mi)
        #pragma unroll
        for (int r = 0; r < 4; ++r) {
            const int row = bm + wm * 32 + mi * 16 + quad * 4 + r;
            #pragma unroll
            for (int ni = 0; ni < 4; ++ni) {
                const int col = bn + wn * 64 + ni * 16 + lm;
                out[(size_t)row * D_MODEL + col] = acc[mi][ni][r] + bb[ni];
            }
        }
}

// ---------------------------------------------------------------------------
// MFMA flash attention (R6 version -- best measured, 46.2us):
// S^T form, 32x32x16, in-register P transpose (permlane32_swap), no split-S,
// fused normalization, QK one-tile-ahead pipeline, triple-buffered KV,
// l-sum via MFMA with all-ones B.
// ---------------------------------------------------------------------------
__global__ __launch_bounds__(256, 2) void attn_mfma(
    const unsigned short* __restrict__ Q, const unsigned short* __restrict__ K,
    const unsigned short* __restrict__ V, unsigned short* __restrict__ Cx)
{
    __shared__ __align__(16) unsigned char raw[49152];
    // buf b (b=0..2): Ks at raw + b*16384 ([2][64][32] ushorts), Vs at +8192
    unsigned short (*Qs)[128][32] = (unsigned short (*)[128][32])raw; // = buf0

    const int t = threadIdx.x, lane = t & 63, w = t >> 6;
    const int q5 = lane & 31, hi = lane >> 5;
    const int lr = lane >> 2, lcs = STAGE_OFS(lane);
    // T1: XCD-chunked swizzle of the 512-block grid
    const int id  = blockIdx.y * 16 + blockIdx.x;   // dispatch-linear id
    const int swz = (id & 7) * 64 + (id >> 3);      // bijective remap
    const int q0 = (swz & 15) * 128, bh = swz >> 4;
    const int sw = (q5 >> 1) & 3;              // row-swizzle for frag reads
    int sbo[4];
    #pragma unroll
    for (int sb = 0; sb < 4; ++sb) sbo[sb] = (sb ^ sw) * 8;

    const unsigned short* Qh = Q + (size_t)bh * (S_LEN * DHEAD);
    const unsigned short* Kh = K + (size_t)bh * (S_LEN * DHEAD);
    const unsigned short* Vh = V + (size_t)bh * (DHEAD * S_LEN);

    // stage Q tile once into buf0 alias: wave w stages rows w*32..w*32+31
    #pragma unroll
    for (int i = 0; i < 2; ++i)
        #pragma unroll
        for (int c = 0; c < 2; ++c)
            GLOAD16(Qh + (size_t)(q0 + w * 32 + c * 16 + lr) * DHEAD + i * 32 + lcs,
                    &Qs[i][w * 32 + c * 16][0]);
    __syncthreads();

    // hoist Q B-frags into registers
    short8 qf[4];
    #pragma unroll
    for (int c = 0; c < 4; ++c)
        qf[c] = *(const short8*)&Qs[c >> 1][w * 32 + q5][sbo[(c & 1) * 2 + hi]];
    __syncthreads();                           // Qs dead; buf0 reusable

    // all-ones B-frag (bf16 1.0 = 0x3F80) for the l-sum MFMA
    short8 onesf;
    #pragma unroll
    for (int j = 0; j < 8; ++j) onesf[j] = (short)0x3F80;

    // stage K/V tile `IT` into buffer BUF (8KB Ks + 8KB Vs)
    #define STAGE_KV(IT, BUF) do {                                            \
        const int kt_ = (IT) * 64;                                            \
        unsigned short* ksb_ = (unsigned short*)(raw + (BUF) * 16384);        \
        unsigned short* vsb_ = ksb_ + 4096;                                   \
        _Pragma("unroll")                                                     \
        for (int i_ = 0; i_ < 2; ++i_) {                                      \
            GLOAD16(Kh + (size_t)(kt_ + w * 16 + lr) * DHEAD + i_ * 32 + lcs, \
                    ksb_ + (i_ * 64 + w * 16) * 32);                          \
            GLOAD16(Vh + (size_t)(w * 16 + lr) * S_LEN + kt_ + i_ * 32 + lcs, \
                    vsb_ + (i_ * 64 + w * 16) * 32);                          \
        }                                                                     \
    } while (0)

    // QK chain for tile IT from its buffer into SF (must be pre-zeroed)
    #define QK_CHAIN(IT, SF) do {                                             \
        const unsigned short* kn_ = (const unsigned short*)                   \
            (raw + ((IT) % 3) * 16384);                                       \
        _Pragma("unroll")                                                     \
        for (int c_ = 0; c_ < 4; ++c_) {                                      \
            _Pragma("unroll")                                                 \
            for (int mt_ = 0; mt_ < 2; ++mt_) {                               \
                const short8 kf_ = *(const short8*)                           \
                    &kn_[((c_ >> 1) * 64 + mt_ * 32 + q5) * 32                \
                         + sbo[(c_ & 1) * 2 + hi]];                           \
                SF[mt_] = __builtin_amdgcn_mfma_f32_32x32x16_bf16(            \
                    kf_, qf[c_], SF[mt_], 0, 0, 0);                           \
            }                                                                 \
        }                                                                     \
    } while (0)

    f32x16 acc[2];     // O strip: [d-tile][16 regs], row=q, col=d
    f32x16 acc_l;      // l (row-sum) via P x ones; same row layout as acc
    ZERO16(acc[0]); ZERO16(acc[1]); ZERO16(acc_l);
    f32x16 sfA[2], sfB[2];

    // prologue: KV(0) resident; sfA = S(0); KV(1) in flight
    STAGE_KV(0, 0);
    __syncthreads();
    ZERO16(sfA[0]); ZERO16(sfA[1]);
    QK_CHAIN(0, sfA);
    STAGE_KV(1, 1);

    // Region R(it): barrier (drains stage(it+1)); issue stage(it+2);
    // QK(it+1) -> SFN; exp/pack/PV/l(it) from SFC.
    #define REGION(IT, SFC, SFN, DOQK) do {                                   \
        __syncthreads();                                                      \
        if ((IT) + 2 < 32) STAGE_KV((IT) + 2, ((IT) + 2) % 3);                \
        if (DOQK) {                                                           \
            ZERO16(SFN[0]); ZERO16(SFN[1]);                                   \
            QK_CHAIN((IT) + 1, SFN);                                          \
        }                                                                     \
        const unsigned short* vs_ = (const unsigned short*)                   \
            (raw + ((IT) % 3) * 16384) + 4096;                                \
        _Pragma("unroll")                                                     \
        for (int c = 0; c < 4; ++c) {                                         \
            const int mt = c >> 1, pp = c & 1;                                \
            float p[8];                                                       \
            _Pragma("unroll")                                                 \
            for (int e = 0; e < 8; ++e)                                       \
                p[e] = __ocml_native_exp2_f32(SFC[mt][pp * 8 + e]);           \
            const unsigned int dA = cvtpk(p[0], p[1]);                        \
            const unsigned int dB = cvtpk(p[2], p[3]);                        \
            const unsigned int sA = cvtpk(p[4], p[5]);                        \
            const unsigned int sB = cvtpk(p[6], p[7]);                        \
            const uint2v wA = __builtin_amdgcn_permlane32_swap(dA, sA, false, false); \
            const uint2v wB = __builtin_amdgcn_permlane32_swap(dB, sB, false, false); \
            uint4v wrds;                                                      \
            wrds.x = wA.x; wrds.y = wB.x; wrds.z = wA.y; wrds.w = wB.y;       \
            const short8 pf = __builtin_bit_cast(short8, wrds);               \
            acc_l = __builtin_amdgcn_mfma_f32_32x32x16_bf16(                  \
                pf, onesf, acc_l, 0, 0, 0);                                   \
            _Pragma("unroll")                                                 \
            for (int nt = 0; nt < 2; ++nt) {                                  \
                const short8 vf = *(const short8*)                            \
                    &vs_[((c >> 1) * 64 + nt * 32 + q5) * 32                  \
                         + sbo[(c & 1) * 2 + hi]];                            \
                acc[nt] = __builtin_amdgcn_mfma_f32_32x32x16_bf16(            \
                    pf, vf, acc[nt], 0, 0, 0);                                \
            }                                                                 \
        }                                                                     \
    } while (0)

    for (int itp = 0; itp < 16; ++itp) {
        const int it0 = itp * 2;
        REGION(it0, sfA, sfB, true);
        REGION(it0 + 1, sfB, sfA, (it0 + 2) < 32);
    }
    #undef REGION
    #undef QK_CHAIN
    #undef STAGE_KV

    // ---- epilogue: l is complete per-lane in acc_l; normalize + write ----
    const int b = bh >> 4, h = bh & 15;
    #pragma unroll
    for (int reg = 0; reg < 16; ++reg) {
        const int row = (reg & 3) + 8 * (reg >> 2) + 4 * hi;
        const float inv = 1.f / acc_l[reg];
        const int q = q0 + w * 32 + row;       // s index within this head
        unsigned short* dst = &Cx[((size_t)(b * S_LEN + q)) * D_MODEL + h * 64];
        dst[q5]      = f2b(acc[0][reg] * inv);
        dst[32 + q5] = f2b(acc[1][reg] * inv);
    }
}

// ---------------------------------------------------------------------------
extern "C" void kernel_launch(void* const* d_in, const int* in_sizes, int n_in,
                              void* d_out, int out_size, void* d_ws, size_t ws_size,
                              hipStream_t stream)
{
    const float* x  = (const float*)d_in[0];
    const float* Wq = (const float*)d_in[1];
    const float* bq = (const float*)d_in[2];
    const float* Wk = (const float*)d_in[3];
    const float* bk = (const float*)d_in[4];
    const float* Wv = (const float*)d_in[5];
    const float* bv = (const float*)d_in[6];
    const float* Wo = (const float*)d_in[7];
    const float* bo = (const float*)d_in[8];
    float* out = (float*)d_out;

    // ws layout (ushort units), 40MB total. Cxb ALIASES xb (xb dead after
    // gemm_qkv; attn writes Cxb, gemm_out reads it).
    unsigned short* base = (unsigned short*)d_ws;
    unsigned short* Wot   = base;                   //  0M .. 1M
    unsigned short* Qb    = base + 1 * MEG;         //  1M .. 5M
    unsigned short* Kb    = base + 5 * MEG;         //  5M .. 9M
    unsigned short* Vt    = base + 9 * MEG;         //  9M ..13M
    unsigned short* xb    = base + 13 * MEG;        // 13M ..17M
    unsigned short* Wqt   = base + 17 * MEG;        // 17M ..18M
    unsigned short* Wkt   = base + 18 * MEG;        // 18M ..19M
    unsigned short* Wvt   = base + 19 * MEG;        // 19M ..20M
    unsigned short* Cxb   = xb;                     // aliases xb

    prep<<<dim3(32, 32, 5), dim3(32, 8), 0, stream>>>(
        x, xb, Wq, Wk, Wv, Wo, Wqt, Wkt, Wvt, Wot);

    gemm_qkv<<<dim3(D_MODEL / 128, M_ROWS / 128, 3), dim3(256), 0, stream>>>(
        xb, Wqt, Wkt, Wvt, bq, bk, bv, Qb, Kb, Vt);

    attn_mfma<<<dim3(S_LEN / 128, BHEADS), dim3(256), 0, stream>>>(
        Qb, Kb, Vt, Cxb);

    gemm_out<<<dim3(D_MODEL / 128, M_ROWS / 64), dim3(256), 0, stream>>>(
        Cxb, Wot, bo, out);
}